// Round 6
// baseline (345.939 us; speedup 1.0000x reference)
//
#include <hip/hip_runtime.h>
#include <hip/hip_bf16.h>

// ---------------------------------------------------------------------------
// SelfAttentionLayer fused pipeline for MI355X (gfx950)
// B=4, S=2048, E=1024, H=16, D=64.  ALL tensor inputs/outputs are FP32;
// compute internally in bf16 MFMA + fp32 accum.
// Round 13 (3rd submit; rounds 4/5 were broker/container failures, no data):
// exact round-9 structure (verified 94.7us attn).  Two non-structural deltas:
//   (a) XCD swizzle: with grid (8,64) x-fastest, xcd = lin&7 = qt, so the
//       8 q-tile blocks sharing a head's K/V landed on 8 DIFFERENT XCDs;
//       each XCD streamed K/V of all 64 heads (32MB) through its 4MB L2.
//       Remap bh=(lin&7)*8+((lin>>3)&7), qt=lin>>6 (bijective) -> all 8
//       q-tiles of a head on one XCD; per-XCD K/V set = 8 heads x 512KB
//       = 4MB = L2-sized.  Staging latency L3/HBM -> L2.
//   (b) mask row staged ONCE pre-loop as pre-scaled bf16 (4KB LDS);
//       removes the per-iter global mask load + if(t<64) divergence from
//       the staging window.  Bias C-init now pure lgkmcnt path.
// Everything else byte-identical to round 9.
// ws layout:
//   Wt   : 4 x 1024x1024 bf16 (Wq^T,Wk^T,Wv^T,Wo^T)   8 MB
//   Xb   : (B*S, E) bf16 (x down-converted)           16 MB
//   Qb   : (B,H,S,D) bf16 (pre-scaled by log2e/32)    16 MB
//   Kb   : (B,H,S,D) bf16                             16 MB
//   Vtb  : (B,H,D,S) bf16                             16 MB
//   Ctx  : (B,S,E)  bf16                              16 MB
//   Add  : (B,S,E)  fp32 (proj + bias + residual)     32 MB
// ---------------------------------------------------------------------------

typedef __bf16 bf16_t;
typedef __bf16 bf16x8 __attribute__((ext_vector_type(8)));
typedef __bf16 bf16x4v __attribute__((ext_vector_type(4)));
typedef float f32x4 __attribute__((ext_vector_type(4)));

#define LDS_AS __attribute__((address_space(3)))
#define GLB_AS __attribute__((address_space(1)))

__device__ __forceinline__ void async16(bf16_t* lds, const bf16_t* g) {
  __builtin_amdgcn_global_load_lds((GLB_AS void*)const_cast<bf16_t*>(g),
                                   (LDS_AS void*)lds, 16, 0, 0);
}

__device__ __forceinline__ f32x4 mfma16(bf16x8 a, bf16x8 b, f32x4 c) {
  return __builtin_amdgcn_mfma_f32_16x16x32_bf16(a, b, c, 0, 0, 0);
}

__device__ __forceinline__ float fast_exp2(float x) {
#if __has_builtin(__builtin_amdgcn_exp2f)
  return __builtin_amdgcn_exp2f(x);
#else
  return __expf(x * 0.6931471805599453f);
#endif
}

// ---------------------------------------------------------------------------
// Kernel 1: weight transpose+cvt (z=0..3) and x fp32->bf16 (z=4)
// ---------------------------------------------------------------------------
__global__ __launch_bounds__(256) void prep_k(
    const float* __restrict__ w0, const float* __restrict__ w1,
    const float* __restrict__ w2, const float* __restrict__ w3,
    bf16_t* __restrict__ dst,
    const float* __restrict__ x, bf16_t* __restrict__ xb)
{
  const int tx = threadIdx.x, ty = threadIdx.y;
  if (blockIdx.z == 4) {
    // cvt x: 8192*1024 floats, 1024 blocks * 256 thr * 8 iters * 4 floats
    const int id = (blockIdx.y * 32 + blockIdx.x) * 256 + ty * 32 + tx;
#pragma unroll
    for (int it = 0; it < 8; ++it) {
      const size_t i = ((size_t)id + (size_t)it * 262144) * 4;
      const float4 v = *(const float4*)(x + i);
      bf16x4v o;
      o[0] = (bf16_t)v.x; o[1] = (bf16_t)v.y; o[2] = (bf16_t)v.z; o[3] = (bf16_t)v.w;
      *(bf16x4v*)(xb + i) = o;
    }
    return;
  }
  __shared__ bf16_t tile[32][33];
  const float* src = (blockIdx.z == 0) ? w0 : (blockIdx.z == 1) ? w1
                   : (blockIdx.z == 2) ? w2 : w3;
  bf16_t* d = dst + (size_t)blockIdx.z * 1024 * 1024;
  const int bx = blockIdx.x * 32, by = blockIdx.y * 32;
#pragma unroll
  for (int r = 0; r < 32; r += 8)
    tile[ty + r][tx] = (bf16_t)src[(size_t)(by + ty + r) * 1024 + bx + tx];
  __syncthreads();
#pragma unroll
  for (int r = 0; r < 32; r += 8)
    d[(size_t)(bx + ty + r) * 1024 + by + tx] = tile[tx][ty + r];
}

// ---------------------------------------------------------------------------
// Kernel 2: QKV GEMM, BK=64 (round-8 form, unchanged).
// ---------------------------------------------------------------------------
__global__ __launch_bounds__(256) void gemm_qkv(
    const bf16_t* __restrict__ X, const bf16_t* __restrict__ WtAll,
    const float* __restrict__ bq, const float* __restrict__ bk,
    const float* __restrict__ bv,
    bf16_t* __restrict__ Qb, bf16_t* __restrict__ Kb, bf16_t* __restrict__ Vtb)
{
  __shared__ __align__(16) bf16_t As[128 * 64];
  __shared__ __align__(16) bf16_t Bs[128 * 64];

  const int z = blockIdx.z;
  const bf16_t* Bt = WtAll + (size_t)z * 1024 * 1024;
  const float* bias = (z == 0) ? bq : (z == 1) ? bk : bv;
  const int bm0 = blockIdx.x * 128;
  const int bn0 = blockIdx.y * 128;
  const int t = threadIdx.x;
  const int w = t >> 6, lane = t & 63;
  const int wm = w >> 1, wn = w & 1;
  const int l15 = lane & 15, quad = lane >> 4;
  const int srow8 = lane >> 3;
  const int sp8   = lane & 7;

  f32x4 acc[4][4] = {};

  for (int k0 = 0; k0 < 1024; k0 += 64) {
    __syncthreads();
#pragma unroll
    for (int i = 0; i < 4; ++i) {
      const int row = (w * 4 + i) * 8 + srow8;
      const int c = sp8 ^ (row & 7);
      async16(&As[row * 64 + sp8 * 8], X  + (size_t)(bm0 + row) * 1024 + k0 + c * 8);
      async16(&Bs[row * 64 + sp8 * 8], Bt + (size_t)(bn0 + row) * 1024 + k0 + c * 8);
    }
    __syncthreads();

    bf16x8 af[4][2], bfr[4][2];
#pragma unroll
    for (int mi = 0; mi < 4; ++mi) {
      const int r = wm * 64 + mi * 16 + l15;
#pragma unroll
      for (int kc = 0; kc < 2; ++kc) {
        const int pg = (kc * 4 + quad) ^ (r & 7);
        af[mi][kc] = *(const bf16x8*)&As[r * 64 + pg * 8];
      }
    }
#pragma unroll
    for (int ni = 0; ni < 4; ++ni) {
      const int r = wn * 64 + ni * 16 + l15;
#pragma unroll
      for (int kc = 0; kc < 2; ++kc) {
        const int pg = (kc * 4 + quad) ^ (r & 7);
        bfr[ni][kc] = *(const bf16x8*)&Bs[r * 64 + pg * 8];
      }
    }
#pragma unroll
    for (int kc = 0; kc < 2; ++kc)
#pragma unroll
      for (int mi = 0; mi < 4; ++mi)
#pragma unroll
        for (int ni = 0; ni < 4; ++ni)
          acc[mi][ni] = mfma16(af[mi][kc], bfr[ni][kc], acc[mi][ni]);
  }

  const float QSCALE = 0.045084220f;  // log2(e)/32

#pragma unroll
  for (int ni = 0; ni < 4; ++ni) {
    const int n = bn0 + wn * 64 + ni * 16 + l15;
    const float bb = bias[n];
    const int h = n >> 6, dd = n & 63;
    if (z == 2) {
#pragma unroll
      for (int mi = 0; mi < 4; ++mi) {
        const int m0 = bm0 + wm * 64 + mi * 16 + quad * 4;
        const int bi = m0 >> 11, s = m0 & 2047;
        bf16x4v vk;
#pragma unroll
        for (int r = 0; r < 4; ++r) vk[r] = (bf16_t)(acc[mi][ni][r] + bb);
        *(bf16x4v*)&Vtb[((size_t)(bi * 16 + h) * 64 + dd) * 2048 + s] = vk;
      }
    } else {
#pragma unroll
      for (int mi = 0; mi < 4; ++mi) {
#pragma unroll
        for (int r = 0; r < 4; ++r) {
          const int m = bm0 + wm * 64 + mi * 16 + quad * 4 + r;
          const float v = acc[mi][ni][r] + bb;
          const int bi = m >> 11, s = m & 2047;
          if (z == 0)
            Qb[((size_t)(bi * 16 + h) * 2048 + s) * 64 + dd] = (bf16_t)(v * QSCALE);
          else
            Kb[((size_t)(bi * 16 + h) * 2048 + s) * 64 + dd] = (bf16_t)v;
        }
      }
    }
  }
}

// ---------------------------------------------------------------------------
// Kernel 3: flash attention, S^T formulation, fixed-max exp2 softmax.
// Round-9 structure exactly (Q-tile 256, 64 q/wave, serial staging, two
// barriers/iter).  Deltas: XCD swizzle so a head's 8 q-tiles share one XCD
// (K/V L2-resident); mask row staged once pre-loop as pre-scaled bf16.
// ---------------------------------------------------------------------------
__global__ __launch_bounds__(256) void attn_k(
    const bf16_t* __restrict__ Qb, const bf16_t* __restrict__ Kb,
    const bf16_t* __restrict__ Vtb, const float* __restrict__ mask,
    bf16_t* __restrict__ Ctx)
{
  __shared__ __align__(16) bf16_t Ks[64 * 64];   // [s_k][d], swizzled granules
  __shared__ __align__(16) bf16_t Vs[64 * 64];   // [d][s_k], swizzled granules
  __shared__ __align__(16) bf16_t Ps[256 * 64];  // [q][s_k], swizzled granules
  __shared__ __align__(16) bf16_t maskb[2048];   // bias row: mask*(-log2e*1e9)

  // XCD swizzle: dispatch-linear lin -> xcd = lin&7 (round-robin heuristic).
  // Map so bh>>3 == lin&7: all 8 q-tiles of a head land on one XCD, whose
  // K/V working set (8 heads x 512KB = 4MB) fits its private L2.
  const int lin = blockIdx.y * 8 + blockIdx.x;
  const int qt = lin >> 6;                          // 0..7
  const int bh = (lin & 7) * 8 + ((lin >> 3) & 7);  // 0..63, bijective
  const int bi = bh >> 4, h = bh & 15;
  const int q0 = qt * 256;
  const bf16_t* Qh = Qb + (size_t)bh * 2048 * 64;
  const bf16_t* Kh = Kb + (size_t)bh * 2048 * 64;
  const bf16_t* Vh = Vtb + (size_t)bh * 64 * 2048;
  const float* mrow = mask + (size_t)bi * 2048;

  const int t = threadIdx.x;
  const int w = t >> 6, lane = t & 63;
  const int l15 = lane & 15, quad = lane >> 4;

  // one-time mask bias staging: 2048 floats -> bf16, pre-scaled
#pragma unroll
  for (int it = 0; it < 2; ++it) {
    const int idx = (it * 256 + t) * 4;
    const float4 mv = *(const float4*)(mrow + idx);
    bf16x4v mb;
    mb[0] = (bf16_t)(mv.x * (-1.442695e9f));
    mb[1] = (bf16_t)(mv.y * (-1.442695e9f));
    mb[2] = (bf16_t)(mv.z * (-1.442695e9f));
    mb[3] = (bf16_t)(mv.w * (-1.442695e9f));
    *(bf16x4v*)&maskb[idx] = mb;
  }

  // Q as B-fragments: q = q0 + w*64 + ni*16 + l15, k = kc*32 + quad*8 + j
  bf16x8 qb[4][2];
#pragma unroll
  for (int ni = 0; ni < 4; ++ni)
#pragma unroll
    for (int kc = 0; kc < 2; ++kc)
      qb[ni][kc] = *(const bf16x8*)&Qh[(size_t)(q0 + w * 64 + ni * 16 + l15) * 64
                                       + kc * 32 + quad * 8];

  bf16x8 ones;
#pragma unroll
  for (int i = 0; i < 8; ++i) ones[i] = (bf16_t)1.0f;

  f32x4 oacc[4][4] = {};      // [d-tile][q-tile]
  f32x4 lacc[4] = {};         // row sums via ones-MFMA

  const int srow = lane >> 3;
  const int sp = lane & 7;

  for (int j = 0; j < 32; ++j) {
    const int k0 = j * 64;
    __syncthreads();
#pragma unroll
    for (int i = 0; i < 2; ++i) {
      const int row = (w * 2 + i) * 8 + srow;
      const int c = sp ^ (row & 7);
      async16(&Ks[row * 64 + sp * 8], Kh + (size_t)(k0 + row) * 64 + c * 8);
      async16(&Vs[row * 64 + sp * 8], Vh + (size_t)row * 2048 + k0 + c * 8);
    }
    __syncthreads();

    // S^T = K . Q^T, C initialized to the mask bias (bf16 LDS, lgkm path)
    f32x4 sacc[4][4];
#pragma unroll
    for (int mi = 0; mi < 4; ++mi) {
      const bf16x4v mb = *(const bf16x4v*)&maskb[k0 + mi * 16 + quad * 4];
      f32x4 ci;
      ci[0] = (float)mb[0]; ci[1] = (float)mb[1];
      ci[2] = (float)mb[2]; ci[3] = (float)mb[3];
#pragma unroll
      for (int ni = 0; ni < 4; ++ni) sacc[mi][ni] = ci;
    }
#pragma unroll
    for (int mi = 0; mi < 4; ++mi) {
      const int r = mi * 16 + l15;
      const bf16x8 kf0 = *(const bf16x8*)&Ks[r * 64 + ((0 * 4 + quad) ^ (r & 7)) * 8];
      const bf16x8 kf1 = *(const bf16x8*)&Ks[r * 64 + ((1 * 4 + quad) ^ (r & 7)) * 8];
#pragma unroll
      for (int ni = 0; ni < 4; ++ni) {
        sacc[mi][ni] = mfma16(kf0, qb[ni][0], sacc[mi][ni]);
        sacc[mi][ni] = mfma16(kf1, qb[ni][1], sacc[mi][ni]);
      }
    }

    // P = exp2(s'), packed b64 LDS writes (rows wave-private)
#pragma unroll
    for (int ni = 0; ni < 4; ++ni) {
      const int row = w * 64 + ni * 16 + l15;
#pragma unroll
      for (int mi = 0; mi < 4; ++mi) {
        bf16x4v pk;
        pk[0] = (bf16_t)fast_exp2(sacc[mi][ni][0]);
        pk[1] = (bf16_t)fast_exp2(sacc[mi][ni][1]);
        pk[2] = (bf16_t)fast_exp2(sacc[mi][ni][2]);
        pk[3] = (bf16_t)fast_exp2(sacc[mi][ni][3]);
        const int pg = (mi * 2 + (quad >> 1)) ^ (row & 7);
        *(bf16x4v*)&Ps[row * 64 + pg * 8 + (quad & 1) * 4] = pk;
      }
    }

    // O^T += V^T . P ; l += ones . P   (av loaded per-mi; Ps wave-private)
    bf16x8 pb[4][2];
#pragma unroll
    for (int ni = 0; ni < 4; ++ni)
#pragma unroll
      for (int kc = 0; kc < 2; ++kc) {
        const int row = w * 64 + ni * 16 + l15;
        const int pg = (kc * 4 + quad) ^ (row & 7);
        pb[ni][kc] = *(const bf16x8*)&Ps[row * 64 + pg * 8];
      }
#pragma unroll
    for (int mi = 0; mi < 4; ++mi) {
      const int r = mi * 16 + l15;
      const bf16x8 av0 = *(const bf16x8*)&Vs[r * 64 + ((0 * 4 + quad) ^ (r & 7)) * 8];
      const bf16x8 av1 = *(const bf16x8*)&Vs[r * 64 + ((1 * 4 + quad) ^ (r & 7)) * 8];
#pragma unroll
      for (int ni = 0; ni < 4; ++ni) {
        oacc[mi][ni] = mfma16(av0, pb[ni][0], oacc[mi][ni]);
        oacc[mi][ni] = mfma16(av1, pb[ni][1], oacc[mi][ni]);
      }
    }
#pragma unroll
    for (int ni = 0; ni < 4; ++ni) {
      lacc[ni] = mfma16(ones, pb[ni][0], lacc[ni]);
      lacc[ni] = mfma16(ones, pb[ni][1], lacc[ni]);
    }
  }

  // write ctx (B,S,E): lane holds O[q = ni*16+l15][d = mi*16+quad*4+r]
#pragma unroll
  for (int ni = 0; ni < 4; ++ni) {
    const float inv = 1.0f / lacc[ni][0];
    const int s = q0 + w * 64 + ni * 16 + l15;
#pragma unroll
    for (int mi = 0; mi < 4; ++mi) {
      bf16x4v o4;
      o4[0] = (bf16_t)(oacc[mi][ni][0] * inv);
      o4[1] = (bf16_t)(oacc[mi][ni][1] * inv);
      o4[2] = (bf16_t)(oacc[mi][ni][2] * inv);
      o4[3] = (bf16_t)(oacc[mi][ni][3] * inv);
      *(bf16x4v*)&Ctx[((size_t)bi * 2048 + s) * 1024 + h * 64 + mi * 16 + quad * 4] = o4;
    }
  }
}

// ---------------------------------------------------------------------------
// Kernel 4: output projection + bias + residual -> fp32 Add (round-8 form).
// ---------------------------------------------------------------------------
__global__ __launch_bounds__(256) void gemm_proj(
    const bf16_t* __restrict__ Ctx, const bf16_t* __restrict__ WoT,
    const float* __restrict__ bo, const float* __restrict__ Xres,
    float* __restrict__ Add)
{
  __shared__ __align__(16) bf16_t As[128 * 64];
  __shared__ __align__(16) bf16_t Bs[128 * 64];

  const int bm0 = blockIdx.x * 128;
  const int bn0 = blockIdx.y * 128;
  const int t = threadIdx.x;
  const int w = t >> 6, lane = t & 63;
  const int wm = w >> 1, wn = w & 1;
  const int l15 = lane & 15, quad = lane >> 4;
  const int srow8 = lane >> 3;
  const int sp8   = lane & 7;

  f32x4 acc[4][4] = {};

  for (int k0 = 0; k0 < 1024; k0 += 64) {
    __syncthreads();
#pragma unroll
    for (int i = 0; i < 4; ++i) {
      const int row = (w * 4 + i) * 8 + srow8;
      const int c = sp8 ^ (row & 7);
      async16(&As[row * 64 + sp8 * 8], Ctx + (size_t)(bm0 + row) * 1024 + k0 + c * 8);
      async16(&Bs[row * 64 + sp8 * 8], WoT + (size_t)(bn0 + row) * 1024 + k0 + c * 8);
    }
    __syncthreads();

    bf16x8 af[4][2], bfr[4][2];
#pragma unroll
    for (int mi = 0; mi < 4; ++mi) {
      const int r = wm * 64 + mi * 16 + l15;
#pragma unroll
      for (int kc = 0; kc < 2; ++kc) {
        const int pg = (kc * 4 + quad) ^ (r & 7);
        af[mi][kc] = *(const bf16x8*)&As[r * 64 + pg * 8];
      }
    }
#pragma unroll
    for (int ni = 0; ni < 4; ++ni) {
      const int r = wn * 64 + ni * 16 + l15;
#pragma unroll
      for (int kc = 0; kc < 2; ++kc) {
        const int pg = (kc * 4 + quad) ^ (r & 7);
        bfr[ni][kc] = *(const bf16x8*)&Bs[r * 64 + pg * 8];
      }
    }
#pragma unroll
    for (int kc = 0; kc < 2; ++kc)
#pragma unroll
      for (int mi = 0; mi < 4; ++mi)
#pragma unroll
        for (int ni = 0; ni < 4; ++ni)
          acc[mi][ni] = mfma16(af[mi][kc], bfr[ni][kc], acc[mi][ni]);
  }

#pragma unroll
  for (int ni = 0; ni < 4; ++ni) {
    const int n = bn0 + wn * 64 + ni * 16 + l15;
    const float bb = bo[n];
#pragma unroll
    for (int mi = 0; mi < 4; ++mi) {
#pragma unroll
      for (int r = 0; r < 4; ++r) {
        const int m = bm0 + wm * 64 + mi * 16 + quad * 4 + r;
        Add[(size_t)m * 1024 + n] =
            acc[mi][ni][r] + bb + Xres[(size_t)m * 1024 + n];
      }
    }
  }
}

// ---------------------------------------------------------------------------
// Kernel 5: LayerNorm, wave-per-row (4 rows / 256-thr block), no LDS/barriers
// ---------------------------------------------------------------------------
__global__ __launch_bounds__(256) void ln_k(
    const float* __restrict__ A, const float* __restrict__ gamma,
    const float* __restrict__ beta, float* __restrict__ out)
{
  const int wid = threadIdx.x >> 6, lane = threadIdx.x & 63;
  const int row = blockIdx.x * 4 + wid;
  const float* a = A + (size_t)row * 1024;

  float4 v[4];
#pragma unroll
  for (int k = 0; k < 4; ++k) v[k] = ((const float4*)a)[lane + k * 64];

  float s = 0.f;
#pragma unroll
  for (int k = 0; k < 4; ++k) s += (v[k].x + v[k].y) + (v[k].z + v[k].w);
#pragma unroll
  for (int o = 1; o < 64; o <<= 1) s += __shfl_xor(s, o);
  const float mu = s * (1.0f / 1024.0f);

  float q = 0.f;
#pragma unroll
  for (int k = 0; k < 4; ++k) {
    v[k].x -= mu; v[k].y -= mu; v[k].z -= mu; v[k].w -= mu;
    q += (v[k].x * v[k].x + v[k].y * v[k].y) + (v[k].z * v[k].z + v[k].w * v[k].w);
  }
#pragma unroll
  for (int o = 1; o < 64; o <<= 1) q += __shfl_xor(q, o);
  const float rs = rsqrtf(q * (1.0f / 1024.0f) + 1e-6f);

#pragma unroll
  for (int k = 0; k < 4; ++k) {
    const int c = lane + k * 64;
    const float4 g4 = ((const float4*)gamma)[c];
    const float4 b4 = ((const float4*)beta)[c];
    float4 o4;
    o4.x = g4.x * v[k].x * rs + b4.x;
    o4.y = g4.y * v[k].y * rs + b4.y;
    o4.z = g4.z * v[k].z * rs + b4.z;
    o4.w = g4.w * v[k].w * rs + b4.w;
    ((float4*)(out + (size_t)row * 1024))[c] = o4;
  }
}

// ---------------------------------------------------------------------------
extern "C" void kernel_launch(void* const* d_in, const int* in_sizes, int n_in,
                              void* d_out, int out_size, void* d_ws, size_t ws_size,
                              hipStream_t stream)
{
  const float* x     = (const float*)d_in[0];
  const float* mask  = (const float*)d_in[1];
  const float* Wq    = (const float*)d_in[2];
  const float* bq    = (const float*)d_in[3];
  const float* Wk    = (const float*)d_in[4];
  const float* bk    = (const float*)d_in[5];
  const float* Wv    = (const float*)d_in[6];
  const float* bv    = (const float*)d_in[7];
  const float* Wo    = (const float*)d_in[8];
  const float* bo    = (const float*)d_in[9];
  const float* gamma = (const float*)d_in[10];
  const float* beta  = (const float*)d_in[11];
  float* out = (float*)d_out;

  bf16_t* Wt  = (bf16_t*)d_ws;
  bf16_t* Xb  = Wt + (size_t)4 * 1024 * 1024;
  bf16_t* Qb  = Xb + (size_t)8192 * 1024;
  bf16_t* Kb  = Qb + (size_t)8192 * 1024;
  bf16_t* Vtb = Kb + (size_t)8192 * 1024;
  bf16_t* Ctx = Vtb + (size_t)8192 * 1024;
  float*  Add = (float*)(Ctx + (size_t)8192 * 1024);

  prep_k<<<dim3(32, 32, 5), dim3(32, 8), 0, stream>>>(Wq, Wk, Wv, Wo, Wt, x, Xb);
  gemm_qkv<<<dim3(64, 8, 3), 256, 0, stream>>>(Xb, Wt, bq, bk, bv, Qb, Kb, Vtb);
  attn_k<<<dim3(8, 64), 256, 0, stream>>>(Qb, Kb, Vtb, mask, Ctx);
  gemm_proj<<<dim3(64, 8), 256, 0, stream>>>(Ctx, Wt + (size_t)3 * 1024 * 1024, bo, x, Add);
  ln_k<<<2048, 256, 0, stream>>>(Add, gamma, beta, out);
}

// Round 7
// 302.526 us; speedup vs baseline: 1.1435x; 1.1435x over previous
//
#include <hip/hip_runtime.h>
#include <hip/hip_bf16.h>

// ---------------------------------------------------------------------------
// SelfAttentionLayer fused pipeline for MI355X (gfx950)
// B=4, S=2048, E=1024, H=16, D=64.  ALL tensor inputs/outputs are FP32;
// compute internally in bf16 MFMA + fp32 accum.
// Round 14: one-variable experiment on the verified round-9 kernel (94.7us).
//   R13 showed: XCD swizzle cuts FETCH 139->41MB (locality mechanism real)
//   but dur rose to 137us with VGPR 120->164 / occ 18.6->11%.  Across R10-13
//   duration tracks VGPR/occupancy, not the idea under test -> R9's 120-VGPR
//   schedule is a fragile local optimum (rule #19 codegen perturbation).
//   This round: attn_k is BYTE-IDENTICAL to round 9 (incl. per-iter maskv
//   staging -- free under the serial drain discipline) except:
//     (1) XCD swizzle: bh=(lin&7)*8+((lin>>3)&7), qt=lin>>6 (bijective);
//         all 8 q-tiles of a head share one XCD -> K/V L2-resident.
//     (2) __launch_bounds__(256,4): min 4 waves/EU -> VGPR capped at 128,
//         pinning the allocator to R9's regime (R9 used 120; no spill risk).
//   Decisive attribution: dur ~80us -> ship; dur ~137us at VGPR<=128 ->
//   the swizzle itself (lockstep same-address L2 contention) is the poison.
// ws layout:
//   Wt   : 4 x 1024x1024 bf16 (Wq^T,Wk^T,Wv^T,Wo^T)   8 MB
//   Xb   : (B*S, E) bf16 (x down-converted)           16 MB
//   Qb   : (B,H,S,D) bf16 (pre-scaled by log2e/32)    16 MB
//   Kb   : (B,H,S,D) bf16                             16 MB
//   Vtb  : (B,H,D,S) bf16                             16 MB
//   Ctx  : (B,S,E)  bf16                              16 MB
//   Add  : (B,S,E)  fp32 (proj + bias + residual)     32 MB
// ---------------------------------------------------------------------------

typedef __bf16 bf16_t;
typedef __bf16 bf16x8 __attribute__((ext_vector_type(8)));
typedef __bf16 bf16x4v __attribute__((ext_vector_type(4)));
typedef float f32x4 __attribute__((ext_vector_type(4)));

#define LDS_AS __attribute__((address_space(3)))
#define GLB_AS __attribute__((address_space(1)))

__device__ __forceinline__ void async16(bf16_t* lds, const bf16_t* g) {
  __builtin_amdgcn_global_load_lds((GLB_AS void*)const_cast<bf16_t*>(g),
                                   (LDS_AS void*)lds, 16, 0, 0);
}

__device__ __forceinline__ f32x4 mfma16(bf16x8 a, bf16x8 b, f32x4 c) {
  return __builtin_amdgcn_mfma_f32_16x16x32_bf16(a, b, c, 0, 0, 0);
}

__device__ __forceinline__ float fast_exp2(float x) {
#if __has_builtin(__builtin_amdgcn_exp2f)
  return __builtin_amdgcn_exp2f(x);
#else
  return __expf(x * 0.6931471805599453f);
#endif
}

// ---------------------------------------------------------------------------
// Kernel 1: weight transpose+cvt (z=0..3) and x fp32->bf16 (z=4)
// ---------------------------------------------------------------------------
__global__ __launch_bounds__(256) void prep_k(
    const float* __restrict__ w0, const float* __restrict__ w1,
    const float* __restrict__ w2, const float* __restrict__ w3,
    bf16_t* __restrict__ dst,
    const float* __restrict__ x, bf16_t* __restrict__ xb)
{
  const int tx = threadIdx.x, ty = threadIdx.y;
  if (blockIdx.z == 4) {
    // cvt x: 8192*1024 floats, 1024 blocks * 256 thr * 8 iters * 4 floats
    const int id = (blockIdx.y * 32 + blockIdx.x) * 256 + ty * 32 + tx;
#pragma unroll
    for (int it = 0; it < 8; ++it) {
      const size_t i = ((size_t)id + (size_t)it * 262144) * 4;
      const float4 v = *(const float4*)(x + i);
      bf16x4v o;
      o[0] = (bf16_t)v.x; o[1] = (bf16_t)v.y; o[2] = (bf16_t)v.z; o[3] = (bf16_t)v.w;
      *(bf16x4v*)(xb + i) = o;
    }
    return;
  }
  __shared__ bf16_t tile[32][33];
  const float* src = (blockIdx.z == 0) ? w0 : (blockIdx.z == 1) ? w1
                   : (blockIdx.z == 2) ? w2 : w3;
  bf16_t* d = dst + (size_t)blockIdx.z * 1024 * 1024;
  const int bx = blockIdx.x * 32, by = blockIdx.y * 32;
#pragma unroll
  for (int r = 0; r < 32; r += 8)
    tile[ty + r][tx] = (bf16_t)src[(size_t)(by + ty + r) * 1024 + bx + tx];
  __syncthreads();
#pragma unroll
  for (int r = 0; r < 32; r += 8)
    d[(size_t)(bx + ty + r) * 1024 + by + tx] = tile[tx][ty + r];
}

// ---------------------------------------------------------------------------
// Kernel 2: QKV GEMM, BK=64 (round-8 form, unchanged).
// ---------------------------------------------------------------------------
__global__ __launch_bounds__(256) void gemm_qkv(
    const bf16_t* __restrict__ X, const bf16_t* __restrict__ WtAll,
    const float* __restrict__ bq, const float* __restrict__ bk,
    const float* __restrict__ bv,
    bf16_t* __restrict__ Qb, bf16_t* __restrict__ Kb, bf16_t* __restrict__ Vtb)
{
  __shared__ __align__(16) bf16_t As[128 * 64];
  __shared__ __align__(16) bf16_t Bs[128 * 64];

  const int z = blockIdx.z;
  const bf16_t* Bt = WtAll + (size_t)z * 1024 * 1024;
  const float* bias = (z == 0) ? bq : (z == 1) ? bk : bv;
  const int bm0 = blockIdx.x * 128;
  const int bn0 = blockIdx.y * 128;
  const int t = threadIdx.x;
  const int w = t >> 6, lane = t & 63;
  const int wm = w >> 1, wn = w & 1;
  const int l15 = lane & 15, quad = lane >> 4;
  const int srow8 = lane >> 3;
  const int sp8   = lane & 7;

  f32x4 acc[4][4] = {};

  for (int k0 = 0; k0 < 1024; k0 += 64) {
    __syncthreads();
#pragma unroll
    for (int i = 0; i < 4; ++i) {
      const int row = (w * 4 + i) * 8 + srow8;
      const int c = sp8 ^ (row & 7);
      async16(&As[row * 64 + sp8 * 8], X  + (size_t)(bm0 + row) * 1024 + k0 + c * 8);
      async16(&Bs[row * 64 + sp8 * 8], Bt + (size_t)(bn0 + row) * 1024 + k0 + c * 8);
    }
    __syncthreads();

    bf16x8 af[4][2], bfr[4][2];
#pragma unroll
    for (int mi = 0; mi < 4; ++mi) {
      const int r = wm * 64 + mi * 16 + l15;
#pragma unroll
      for (int kc = 0; kc < 2; ++kc) {
        const int pg = (kc * 4 + quad) ^ (r & 7);
        af[mi][kc] = *(const bf16x8*)&As[r * 64 + pg * 8];
      }
    }
#pragma unroll
    for (int ni = 0; ni < 4; ++ni) {
      const int r = wn * 64 + ni * 16 + l15;
#pragma unroll
      for (int kc = 0; kc < 2; ++kc) {
        const int pg = (kc * 4 + quad) ^ (r & 7);
        bfr[ni][kc] = *(const bf16x8*)&Bs[r * 64 + pg * 8];
      }
    }
#pragma unroll
    for (int kc = 0; kc < 2; ++kc)
#pragma unroll
      for (int mi = 0; mi < 4; ++mi)
#pragma unroll
        for (int ni = 0; ni < 4; ++ni)
          acc[mi][ni] = mfma16(af[mi][kc], bfr[ni][kc], acc[mi][ni]);
  }

  const float QSCALE = 0.045084220f;  // log2(e)/32

#pragma unroll
  for (int ni = 0; ni < 4; ++ni) {
    const int n = bn0 + wn * 64 + ni * 16 + l15;
    const float bb = bias[n];
    const int h = n >> 6, dd = n & 63;
    if (z == 2) {
#pragma unroll
      for (int mi = 0; mi < 4; ++mi) {
        const int m0 = bm0 + wm * 64 + mi * 16 + quad * 4;
        const int bi = m0 >> 11, s = m0 & 2047;
        bf16x4v vk;
#pragma unroll
        for (int r = 0; r < 4; ++r) vk[r] = (bf16_t)(acc[mi][ni][r] + bb);
        *(bf16x4v*)&Vtb[((size_t)(bi * 16 + h) * 64 + dd) * 2048 + s] = vk;
      }
    } else {
#pragma unroll
      for (int mi = 0; mi < 4; ++mi) {
#pragma unroll
        for (int r = 0; r < 4; ++r) {
          const int m = bm0 + wm * 64 + mi * 16 + quad * 4 + r;
          const float v = acc[mi][ni][r] + bb;
          const int bi = m >> 11, s = m & 2047;
          if (z == 0)
            Qb[((size_t)(bi * 16 + h) * 2048 + s) * 64 + dd] = (bf16_t)(v * QSCALE);
          else
            Kb[((size_t)(bi * 16 + h) * 2048 + s) * 64 + dd] = (bf16_t)v;
        }
      }
    }
  }
}

// ---------------------------------------------------------------------------
// Kernel 3: flash attention, S^T formulation, fixed-max exp2 softmax.
// BYTE-IDENTICAL to round 9 except: XCD swizzle (qt/bh remap) and
// __launch_bounds__(256,4) pinning VGPR <= 128.
// ---------------------------------------------------------------------------
__global__ __launch_bounds__(256, 4) void attn_k(
    const bf16_t* __restrict__ Qb, const bf16_t* __restrict__ Kb,
    const bf16_t* __restrict__ Vtb, const float* __restrict__ mask,
    bf16_t* __restrict__ Ctx)
{
  __shared__ __align__(16) bf16_t Ks[64 * 64];   // [s_k][d], swizzled granules
  __shared__ __align__(16) bf16_t Vs[64 * 64];   // [d][s_k], swizzled granules
  __shared__ __align__(16) bf16_t Ps[256 * 64];  // [q][s_k], swizzled granules
  __shared__ __align__(16) float maskv[64];

  // XCD swizzle: all 8 q-tiles of a head on one XCD (K/V set 4MB = L2-sized)
  const int lin = blockIdx.y * 8 + blockIdx.x;
  const int qt = lin >> 6;                          // 0..7
  const int bh = (lin & 7) * 8 + ((lin >> 3) & 7);  // 0..63, bijective
  const int bi = bh >> 4, h = bh & 15;
  const int q0 = qt * 256;
  const bf16_t* Qh = Qb + (size_t)bh * 2048 * 64;
  const bf16_t* Kh = Kb + (size_t)bh * 2048 * 64;
  const bf16_t* Vh = Vtb + (size_t)bh * 64 * 2048;

  const int t = threadIdx.x;
  const int w = t >> 6, lane = t & 63;
  const int l15 = lane & 15, quad = lane >> 4;

  // Q as B-fragments: q = q0 + w*64 + ni*16 + l15, k = kc*32 + quad*8 + j
  bf16x8 qb[4][2];
#pragma unroll
  for (int ni = 0; ni < 4; ++ni)
#pragma unroll
    for (int kc = 0; kc < 2; ++kc)
      qb[ni][kc] = *(const bf16x8*)&Qh[(size_t)(q0 + w * 64 + ni * 16 + l15) * 64
                                       + kc * 32 + quad * 8];

  bf16x8 ones;
#pragma unroll
  for (int i = 0; i < 8; ++i) ones[i] = (bf16_t)1.0f;

  f32x4 oacc[4][4] = {};      // [d-tile][q-tile]
  f32x4 lacc[4] = {};         // row sums via ones-MFMA

  const int srow = lane >> 3;
  const int sp = lane & 7;

  for (int j = 0; j < 32; ++j) {
    const int k0 = j * 64;
    __syncthreads();
#pragma unroll
    for (int i = 0; i < 2; ++i) {
      const int row = (w * 2 + i) * 8 + srow;
      const int c = sp ^ (row & 7);
      async16(&Ks[row * 64 + sp * 8], Kh + (size_t)(k0 + row) * 64 + c * 8);
      async16(&Vs[row * 64 + sp * 8], Vh + (size_t)row * 2048 + k0 + c * 8);
    }
    if (t < 64) maskv[t] = mask[bi * 2048 + k0 + t] * (-1.442695e9f);
    __syncthreads();

    // S^T = K . Q^T, C initialized to the mask bias; kf loaded per-mi
    f32x4 sacc[4][4];
#pragma unroll
    for (int mi = 0; mi < 4; ++mi) {
      const float4 mk = *(const float4*)&maskv[mi * 16 + quad * 4];
      f32x4 cinit; cinit[0] = mk.x; cinit[1] = mk.y; cinit[2] = mk.z; cinit[3] = mk.w;
#pragma unroll
      for (int ni = 0; ni < 4; ++ni) sacc[mi][ni] = cinit;
    }
#pragma unroll
    for (int mi = 0; mi < 4; ++mi) {
      const int r = mi * 16 + l15;
      const bf16x8 kf0 = *(const bf16x8*)&Ks[r * 64 + ((0 * 4 + quad) ^ (r & 7)) * 8];
      const bf16x8 kf1 = *(const bf16x8*)&Ks[r * 64 + ((1 * 4 + quad) ^ (r & 7)) * 8];
#pragma unroll
      for (int ni = 0; ni < 4; ++ni) {
        sacc[mi][ni] = mfma16(kf0, qb[ni][0], sacc[mi][ni]);
        sacc[mi][ni] = mfma16(kf1, qb[ni][1], sacc[mi][ni]);
      }
    }

    // P = exp2(s'), packed b64 LDS writes (rows wave-private)
#pragma unroll
    for (int ni = 0; ni < 4; ++ni) {
      const int row = w * 64 + ni * 16 + l15;
#pragma unroll
      for (int mi = 0; mi < 4; ++mi) {
        bf16x4v pk;
        pk[0] = (bf16_t)fast_exp2(sacc[mi][ni][0]);
        pk[1] = (bf16_t)fast_exp2(sacc[mi][ni][1]);
        pk[2] = (bf16_t)fast_exp2(sacc[mi][ni][2]);
        pk[3] = (bf16_t)fast_exp2(sacc[mi][ni][3]);
        const int pg = (mi * 2 + (quad >> 1)) ^ (row & 7);
        *(bf16x4v*)&Ps[row * 64 + pg * 8 + (quad & 1) * 4] = pk;
      }
    }

    // O^T += V^T . P ; l += ones . P   (av loaded per-mi; Ps wave-private)
    bf16x8 pb[4][2];
#pragma unroll
    for (int ni = 0; ni < 4; ++ni)
#pragma unroll
      for (int kc = 0; kc < 2; ++kc) {
        const int row = w * 64 + ni * 16 + l15;
        const int pg = (kc * 4 + quad) ^ (row & 7);
        pb[ni][kc] = *(const bf16x8*)&Ps[row * 64 + pg * 8];
      }
#pragma unroll
    for (int mi = 0; mi < 4; ++mi) {
      const int r = mi * 16 + l15;
      const bf16x8 av0 = *(const bf16x8*)&Vs[r * 64 + ((0 * 4 + quad) ^ (r & 7)) * 8];
      const bf16x8 av1 = *(const bf16x8*)&Vs[r * 64 + ((1 * 4 + quad) ^ (r & 7)) * 8];
#pragma unroll
      for (int ni = 0; ni < 4; ++ni) {
        oacc[mi][ni] = mfma16(av0, pb[ni][0], oacc[mi][ni]);
        oacc[mi][ni] = mfma16(av1, pb[ni][1], oacc[mi][ni]);
      }
    }
#pragma unroll
    for (int ni = 0; ni < 4; ++ni) {
      lacc[ni] = mfma16(ones, pb[ni][0], lacc[ni]);
      lacc[ni] = mfma16(ones, pb[ni][1], lacc[ni]);
    }
  }

  // write ctx (B,S,E): lane holds O[q = ni*16+l15][d = mi*16+quad*4+r]
#pragma unroll
  for (int ni = 0; ni < 4; ++ni) {
    const float inv = 1.0f / lacc[ni][0];
    const int s = q0 + w * 64 + ni * 16 + l15;
#pragma unroll
    for (int mi = 0; mi < 4; ++mi) {
      bf16x4v o4;
      o4[0] = (bf16_t)(oacc[mi][ni][0] * inv);
      o4[1] = (bf16_t)(oacc[mi][ni][1] * inv);
      o4[2] = (bf16_t)(oacc[mi][ni][2] * inv);
      o4[3] = (bf16_t)(oacc[mi][ni][3] * inv);
      *(bf16x4v*)&Ctx[((size_t)bi * 2048 + s) * 1024 + h * 64 + mi * 16 + quad * 4] = o4;
    }
  }
}

// ---------------------------------------------------------------------------
// Kernel 4: output projection + bias + residual -> fp32 Add (round-8 form).
// ---------------------------------------------------------------------------
__global__ __launch_bounds__(256) void gemm_proj(
    const bf16_t* __restrict__ Ctx, const bf16_t* __restrict__ WoT,
    const float* __restrict__ bo, const float* __restrict__ Xres,
    float* __restrict__ Add)
{
  __shared__ __align__(16) bf16_t As[128 * 64];
  __shared__ __align__(16) bf16_t Bs[128 * 64];

  const int bm0 = blockIdx.x * 128;
  const int bn0 = blockIdx.y * 128;
  const int t = threadIdx.x;
  const int w = t >> 6, lane = t & 63;
  const int wm = w >> 1, wn = w & 1;
  const int l15 = lane & 15, quad = lane >> 4;
  const int srow8 = lane >> 3;
  const int sp8   = lane & 7;

  f32x4 acc[4][4] = {};

  for (int k0 = 0; k0 < 1024; k0 += 64) {
    __syncthreads();
#pragma unroll
    for (int i = 0; i < 4; ++i) {
      const int row = (w * 4 + i) * 8 + srow8;
      const int c = sp8 ^ (row & 7);
      async16(&As[row * 64 + sp8 * 8], Ctx + (size_t)(bm0 + row) * 1024 + k0 + c * 8);
      async16(&Bs[row * 64 + sp8 * 8], WoT + (size_t)(bn0 + row) * 1024 + k0 + c * 8);
    }
    __syncthreads();

    bf16x8 af[4][2], bfr[4][2];
#pragma unroll
    for (int mi = 0; mi < 4; ++mi) {
      const int r = wm * 64 + mi * 16 + l15;
#pragma unroll
      for (int kc = 0; kc < 2; ++kc) {
        const int pg = (kc * 4 + quad) ^ (r & 7);
        af[mi][kc] = *(const bf16x8*)&As[r * 64 + pg * 8];
      }
    }
#pragma unroll
    for (int ni = 0; ni < 4; ++ni) {
      const int r = wn * 64 + ni * 16 + l15;
#pragma unroll
      for (int kc = 0; kc < 2; ++kc) {
        const int pg = (kc * 4 + quad) ^ (r & 7);
        bfr[ni][kc] = *(const bf16x8*)&Bs[r * 64 + pg * 8];
      }
    }
#pragma unroll
    for (int kc = 0; kc < 2; ++kc)
#pragma unroll
      for (int mi = 0; mi < 4; ++mi)
#pragma unroll
        for (int ni = 0; ni < 4; ++ni)
          acc[mi][ni] = mfma16(af[mi][kc], bfr[ni][kc], acc[mi][ni]);
  }

#pragma unroll
  for (int ni = 0; ni < 4; ++ni) {
    const int n = bn0 + wn * 64 + ni * 16 + l15;
    const float bb = bo[n];
#pragma unroll
    for (int mi = 0; mi < 4; ++mi) {
#pragma unroll
      for (int r = 0; r < 4; ++r) {
        const int m = bm0 + wm * 64 + mi * 16 + quad * 4 + r;
        Add[(size_t)m * 1024 + n] =
            acc[mi][ni][r] + bb + Xres[(size_t)m * 1024 + n];
      }
    }
  }
}

// ---------------------------------------------------------------------------
// Kernel 5: LayerNorm, wave-per-row (4 rows / 256-thr block), no LDS/barriers
// ---------------------------------------------------------------------------
__global__ __launch_bounds__(256) void ln_k(
    const float* __restrict__ A, const float* __restrict__ gamma,
    const float* __restrict__ beta, float* __restrict__ out)
{
  const int wid = threadIdx.x >> 6, lane = threadIdx.x & 63;
  const int row = blockIdx.x * 4 + wid;
  const float* a = A + (size_t)row * 1024;

  float4 v[4];
#pragma unroll
  for (int k = 0; k < 4; ++k) v[k] = ((const float4*)a)[lane + k * 64];

  float s = 0.f;
#pragma unroll
  for (int k = 0; k < 4; ++k) s += (v[k].x + v[k].y) + (v[k].z + v[k].w);
#pragma unroll
  for (int o = 1; o < 64; o <<= 1) s += __shfl_xor(s, o);
  const float mu = s * (1.0f / 1024.0f);

  float q = 0.f;
#pragma unroll
  for (int k = 0; k < 4; ++k) {
    v[k].x -= mu; v[k].y -= mu; v[k].z -= mu; v[k].w -= mu;
    q += (v[k].x * v[k].x + v[k].y * v[k].y) + (v[k].z * v[k].z + v[k].w * v[k].w);
  }
#pragma unroll
  for (int o = 1; o < 64; o <<= 1) q += __shfl_xor(q, o);
  const float rs = rsqrtf(q * (1.0f / 1024.0f) + 1e-6f);

#pragma unroll
  for (int k = 0; k < 4; ++k) {
    const int c = lane + k * 64;
    const float4 g4 = ((const float4*)gamma)[c];
    const float4 b4 = ((const float4*)beta)[c];
    float4 o4;
    o4.x = g4.x * v[k].x * rs + b4.x;
    o4.y = g4.y * v[k].y * rs + b4.y;
    o4.z = g4.z * v[k].z * rs + b4.z;
    o4.w = g4.w * v[k].w * rs + b4.w;
    ((float4*)(out + (size_t)row * 1024))[c] = o4;
  }
}

// ---------------------------------------------------------------------------
extern "C" void kernel_launch(void* const* d_in, const int* in_sizes, int n_in,
                              void* d_out, int out_size, void* d_ws, size_t ws_size,
                              hipStream_t stream)
{
  const float* x     = (const float*)d_in[0];
  const float* mask  = (const float*)d_in[1];
  const float* Wq    = (const float*)d_in[2];
  const float* bq    = (const float*)d_in[3];
  const float* Wk    = (const float*)d_in[4];
  const float* bk    = (const float*)d_in[5];
  const float* Wv    = (const float*)d_in[6];
  const float* bv    = (const float*)d_in[7];
  const float* Wo    = (const float*)d_in[8];
  const float* bo    = (const float*)d_in[9];
  const float* gamma = (const float*)d_in[10];
  const float* beta  = (const float*)d_in[11];
  float* out = (float*)d_out;

  bf16_t* Wt  = (bf16_t*)d_ws;
  bf16_t* Xb  = Wt + (size_t)4 * 1024 * 1024;
  bf16_t* Qb  = Xb + (size_t)8192 * 1024;
  bf16_t* Kb  = Qb + (size_t)8192 * 1024;
  bf16_t* Vtb = Kb + (size_t)8192 * 1024;
  bf16_t* Ctx = Vtb + (size_t)8192 * 1024;
  float*  Add = (float*)(Ctx + (size_t)8192 * 1024);

  prep_k<<<dim3(32, 32, 5), dim3(32, 8), 0, stream>>>(Wq, Wk, Wv, Wo, Wt, x, Xb);
  gemm_qkv<<<dim3(64, 8, 3), 256, 0, stream>>>(Xb, Wt, bq, bk, bv, Qb, Kb, Vtb);
  attn_k<<<dim3(8, 64), 256, 0, stream>>>(Qb, Kb, Vtb, mask, Ctx);
  gemm_proj<<<dim3(64, 8), 256, 0, stream>>>(Ctx, Wt + (size_t)3 * 1024 * 1024, bo, x, Add);
  ln_k<<<2048, 256, 0, stream>>>(Add, gamma, beta, out);
}